// Round 1
// baseline (13738.370 us; speedup 1.0000x reference)
//
#include <hip/hip_runtime.h>

// GRU rollout: 257 sequential steps (1 history + 256 rollout).
// Strategy: persistent cooperative kernel, fp16 MFMA 16x16x32, custom
// device-scope barrier once per step. Block cg owns gate-channels
// [cg*16, cg*16+16): computes preact cols {c, H+c, 2H+c} so gates are
// evaluated from MFMA accumulators in registers.
//
// ws layout (needs ~72.1 MB):
//   Wc   fp16 [6144][3072]  combined [W_ih | W_hh], row-major by output col
//   XA   fp16 [257][64][1024] per-step x (t=0 = history_a[:,255])
//   Hbuf fp16 [2][64][2048]  ping-pong h state
//   rpart f32 [2][64][128]   per-block reward-dot partials
//   bar  u32 [2]             {counter, generation}

#define HT   2048
#define INW  1024
#define KTOT 3072
#define G3   6144
#define BB   64
#define TRR  256
#define NSTEP 257
#define NBLK 128
#define NTHR 256

typedef _Float16 f16;
typedef _Float16 half8 __attribute__((ext_vector_type(8)));
typedef _Float16 half4x __attribute__((ext_vector_type(4)));
typedef float v4f __attribute__((ext_vector_type(4)));

__device__ __forceinline__ float sigm_(float x) {
  x = fminf(fmaxf(x, -30.f), 30.f);
  return 1.f / (1.f + __expf(-x));
}
__device__ __forceinline__ float tanh_(float x) {
  x = fminf(fmaxf(x, -15.f), 15.f);
  float e = __expf(2.f * x);
  return (e - 1.f) / (e + 1.f);
}

__global__ void prep_weights(const float* __restrict__ Wih, const float* __restrict__ Whh,
                             f16* __restrict__ Wc) {
  long idx = (long)blockIdx.x * blockDim.x + threadIdx.x;
  const long total = (long)G3 * KTOT / 4;
  if (idx >= total) return;
  long e = idx * 4;
  int j = (int)(e / KTOT);
  int k = (int)(e % KTOT);
  float4 v;
  if (k < INW) v = *(const float4*)(Wih + (long)j * INW + k);
  else         v = *(const float4*)(Whh + (long)j * HT + (k - INW));
  half4x h = { (f16)v.x, (f16)v.y, (f16)v.z, (f16)v.w };
  *(half4x*)(Wc + e) = h;
}

__global__ void prep_inputs(const float* __restrict__ ha, const float* __restrict__ a,
                            const float* __restrict__ hs,
                            f16* __restrict__ XA, f16* __restrict__ H0,
                            unsigned* __restrict__ bar) {
  long idx = (long)blockIdx.x * blockDim.x + threadIdx.x;
  const long nxa = (long)NSTEP * BB * INW / 4;   // 4,210,688
  const long nh  = (long)BB * HT / 4;            // 32,768
  if (idx < nxa) {
    long e = idx * 4;
    int t = (int)(e >> 16);          // / (64*1024)
    int rem = (int)(e & 65535);
    int b = rem >> 10;
    int k = rem & 1023;
    const float* src = (t == 0) ? (ha + ((long)b * TRR + 255) * INW + k)
                                : (a  + ((long)b * TRR + (t - 1)) * INW + k);
    float4 v = *(const float4*)src;
    half4x h = { (f16)v.x, (f16)v.y, (f16)v.z, (f16)v.w };
    *(half4x*)(XA + e) = h;
  } else if (idx < nxa + nh) {
    long e = (idx - nxa) * 4;
    int b = (int)(e >> 11);
    int i = (int)(e & 2047);
    float4 v = *(const float4*)(hs + ((long)b * TRR + 255) * HT + i);
    half4x h = { (f16)v.x, (f16)v.y, (f16)v.z, (f16)v.w };
    *(half4x*)(H0 + e) = h;
  } else if (idx == nxa + nh) {
    bar[0] = 0u;
    bar[1] = 0u;
  }
}

__global__ void __launch_bounds__(NTHR)
gru_persist(const f16* __restrict__ Wc, const f16* __restrict__ XA,
            f16* __restrict__ Hbuf, float* __restrict__ rpart,
            unsigned* __restrict__ bar,
            const float* __restrict__ bih, const float* __restrict__ bhh,
            const float* __restrict__ Wr, const float* __restrict__ brp,
            float* __restrict__ out) {
  const int cg  = blockIdx.x;      // gate-channel group: cols [cg*16, cg*16+16)
  const int c0  = cg * 16;
  const int tid = threadIdx.x;
  const int w   = tid >> 6;        // wave id 0..3 -> row-tile (batch rows 16w..16w+15)
  const int l   = tid & 63;
  const int q   = l >> 4;          // quad
  const int ci  = l & 15;
  const int m0  = w * 16;

  // per-lane gate biases (col j = g*H + c0 + ci), loaded once
  const float bi0 = bih[0 * HT + c0 + ci], bh0 = bhh[0 * HT + c0 + ci];
  const float bi1 = bih[1 * HT + c0 + ci], bh1 = bhh[1 * HT + c0 + ci];
  const float bi2 = bih[2 * HT + c0 + ci], bh2 = bhh[2 * HT + c0 + ci];
  const float wr  = Wr[c0 + ci];
  const float br  = brp[0];
  float* outr = out;                       // [64][256]
  float* outs = out + (long)BB * TRR;      // [64][256][2048]

  // B-fragment row bases: lane ci selects output col, quad selects k-subrange
  const f16* wrow0 = Wc + (long)(0 * HT + c0 + ci) * KTOT + q * 8;
  const f16* wrow1 = Wc + (long)(1 * HT + c0 + ci) * KTOT + q * 8;
  const f16* wrow2 = Wc + (long)(2 * HT + c0 + ci) * KTOT + q * 8;

  for (int t = 0; t <= 256; ++t) {
    const f16* Xa  = XA + (long)t * BB * INW + (long)(m0 + ci) * INW + q * 8;
    const f16* Hin = Hbuf + (long)(t & 1) * BB * HT;
    f16* Hout      = Hbuf + (long)((t + 1) & 1) * BB * HT;

    v4f zero = {0.f, 0.f, 0.f, 0.f};
    v4f acc0 = zero, acc1 = zero, acc2 = zero;   // C_i : gates r,z,n
    v4f acc3 = zero, acc4 = zero, acc5 = zero;   // C_h : gates r,z,n

    // ---- C_i (K=1024 over precomputed XA[t]) — independent of barrier ----
    #pragma unroll 4
    for (int k0 = 0; k0 < INW; k0 += 32) {
      half8 av  = *(const half8*)(Xa + k0);
      half8 bv0 = *(const half8*)(wrow0 + k0);
      half8 bv1 = *(const half8*)(wrow1 + k0);
      half8 bv2 = *(const half8*)(wrow2 + k0);
      acc0 = __builtin_amdgcn_mfma_f32_16x16x32_f16(av, bv0, acc0, 0, 0, 0);
      acc1 = __builtin_amdgcn_mfma_f32_16x16x32_f16(av, bv1, acc1, 0, 0, 0);
      acc2 = __builtin_amdgcn_mfma_f32_16x16x32_f16(av, bv2, acc2, 0, 0, 0);
    }

    // ---- wait for h_{t-1} (generation >= t) ----
    if (t > 0) {
      if (tid == 0) {
        while (__hip_atomic_load(&bar[1], __ATOMIC_ACQUIRE, __HIP_MEMORY_SCOPE_AGENT) < (unsigned)t)
          __builtin_amdgcn_s_sleep(2);
        __threadfence();   // invalidate stale L1/L2 before reading Hin
      }
      __syncthreads();
    }

    // ---- finalize reward r for step t-2 (off critical path) ----
    if (t >= 2 && cg < BB && w == 0) {
      const float* rp = rpart + (long)((t - 1) & 1) * BB * NBLK + (long)cg * NBLK;
      float v = rp[l] + rp[l + 64];
      v += __shfl_xor(v, 32, 64); v += __shfl_xor(v, 16, 64);
      v += __shfl_xor(v, 8, 64);  v += __shfl_xor(v, 4, 64);
      v += __shfl_xor(v, 2, 64);  v += __shfl_xor(v, 1, 64);
      if (l == 0) outr[(long)cg * TRR + (t - 2)] = sigm_(v + br);
    }

    // ---- C_h (K=2048 over Hbuf[t&1]) ----
    {
      const f16* Ha = Hin + (long)(m0 + ci) * HT + q * 8;
      #pragma unroll 4
      for (int k0 = 0; k0 < HT; k0 += 32) {
        half8 av  = *(const half8*)(Ha + k0);
        half8 bv0 = *(const half8*)(wrow0 + INW + k0);
        half8 bv1 = *(const half8*)(wrow1 + INW + k0);
        half8 bv2 = *(const half8*)(wrow2 + INW + k0);
        acc3 = __builtin_amdgcn_mfma_f32_16x16x32_f16(av, bv0, acc3, 0, 0, 0);
        acc4 = __builtin_amdgcn_mfma_f32_16x16x32_f16(av, bv1, acc4, 0, 0, 0);
        acc5 = __builtin_amdgcn_mfma_f32_16x16x32_f16(av, bv2, acc5, 0, 0, 0);
      }
    }

    // ---- gates: all operands live in this lane's registers ----
    // C/D layout: value (b = m0 + 4*q + rr, col = c0 + ci)
    float rd[4];
    const int i = c0 + ci;
    #pragma unroll
    for (int rr = 0; rr < 4; ++rr) {
      const int b = m0 + q * 4 + rr;
      float rg = sigm_(acc0[rr] + bi0 + acc3[rr] + bh0);
      float zg = sigm_(acc1[rr] + bi1 + acc4[rr] + bh1);
      float ng = tanh_(acc2[rr] + bi2 + rg * (acc5[rr] + bh2));
      float hp = (float)Hin[(long)b * HT + i];
      float hn = (1.f - zg) * ng + zg * hp;
      Hout[(long)b * HT + i] = (f16)hn;
      if (t >= 1)
        __builtin_nontemporal_store(hn, outs + ((long)b * TRR + (t - 1)) * HT + i);
      rd[rr] = hn * wr;
    }
    // reward-dot partial: reduce over the 16 cols held by this quad
    #pragma unroll
    for (int rr = 0; rr < 4; ++rr) {
      float v = rd[rr];
      v += __shfl_xor(v, 1, 16); v += __shfl_xor(v, 2, 16);
      v += __shfl_xor(v, 4, 16); v += __shfl_xor(v, 8, 16);
      if (ci == 0)
        rpart[(long)(t & 1) * BB * NBLK + (long)(m0 + q * 4 + rr) * NBLK + cg] = v;
    }

    // ---- arrive ----
    __syncthreads();   // drains each wave's stores (vmcnt 0) before fence
    if (tid == 0) {
      __threadfence(); // write back dirty L2 so other XCDs see Hout/rpart
      unsigned prev = __hip_atomic_fetch_add(&bar[0], 1u, __ATOMIC_ACQ_REL, __HIP_MEMORY_SCOPE_AGENT);
      if (prev == NBLK - 1) {
        __hip_atomic_store(&bar[0], 0u, __ATOMIC_RELAXED, __HIP_MEMORY_SCOPE_AGENT);
        __hip_atomic_store(&bar[1], (unsigned)(t + 1), __ATOMIC_RELEASE, __HIP_MEMORY_SCOPE_AGENT);
      }
    }
  }

  // ---- final reward column (t=256 -> r_list[:,255]) ----
  if (tid == 0) {
    while (__hip_atomic_load(&bar[1], __ATOMIC_ACQUIRE, __HIP_MEMORY_SCOPE_AGENT) < 257u)
      __builtin_amdgcn_s_sleep(2);
    __threadfence();
  }
  __syncthreads();
  if (cg < BB && w == 0) {
    const float* rp = rpart + 0 /* parity of t=256 */ + (long)cg * NBLK;
    float v = rp[l] + rp[l + 64];
    v += __shfl_xor(v, 32, 64); v += __shfl_xor(v, 16, 64);
    v += __shfl_xor(v, 8, 64);  v += __shfl_xor(v, 4, 64);
    v += __shfl_xor(v, 2, 64);  v += __shfl_xor(v, 1, 64);
    if (l == 0) outr[(long)cg * TRR + 255] = sigm_(v + br);
  }
}

extern "C" void kernel_launch(void* const* d_in, const int* in_sizes, int n_in,
                              void* d_out, int out_size, void* d_ws, size_t ws_size,
                              hipStream_t stream) {
  const float* hs  = (const float*)d_in[0];   // history_s_list [64,256,2048]
  const float* ha  = (const float*)d_in[1];   // history_a_list [64,256,1024]
  /* d_in[2] = s — unused by the reference */
  const float* a   = (const float*)d_in[3];   // a_list [64,256,1024]
  const float* Wih = (const float*)d_in[4];   // [6144,1024]
  const float* Whh = (const float*)d_in[5];   // [6144,2048]
  const float* bih = (const float*)d_in[6];
  const float* bhh = (const float*)d_in[7];
  const float* Wr  = (const float*)d_in[8];   // [1,2048]
  const float* br  = (const float*)d_in[9];
  float* out = (float*)d_out;                 // r_list[64][256] ++ s_list[64][256][2048]

  char* ws = (char*)d_ws;
  const size_t oWc = 0;
  const size_t oXA = oWc + (size_t)G3 * KTOT * 2;            // 37,748,736
  const size_t oHb = oXA + (size_t)NSTEP * BB * INW * 2;     // +33,685,504
  const size_t oRp = oHb + (size_t)2 * BB * HT * 2;          // +524,288
  const size_t oBar = oRp + (size_t)2 * BB * NBLK * 4;       // +65,536
  // total ~72.03 MB — assumed <= ws_size
  f16* Wc   = (f16*)(ws + oWc);
  f16* XA   = (f16*)(ws + oXA);
  f16* Hb   = (f16*)(ws + oHb);
  float* rp = (float*)(ws + oRp);
  unsigned* bar = (unsigned*)(ws + oBar);

  {
    long quads = (long)G3 * KTOT / 4;
    prep_weights<<<dim3((unsigned)((quads + 255) / 256)), dim3(256), 0, stream>>>(Wih, Whh, Wc);
  }
  {
    long ntot = (long)NSTEP * BB * INW / 4 + (long)BB * HT / 4 + 1;
    prep_inputs<<<dim3((unsigned)((ntot + 255) / 256)), dim3(256), 0, stream>>>(ha, a, hs, XA, Hb, bar);
  }
  {
    void* args[] = { &Wc, &XA, &Hb, &rp, &bar,
                     (void*)&bih, (void*)&bhh, (void*)&Wr, (void*)&br, &out };
    hipLaunchCooperativeKernel(reinterpret_cast<void*>(gru_persist),
                               dim3(NBLK), dim3(NTHR), args, 0, stream);
  }
}

// Round 2
// 9017.753 us; speedup vs baseline: 1.5235x; 1.5235x over previous
//
#include <hip/hip_runtime.h>

// GRU rollout: 257 sequential steps. v3: LDS-resident weights.
// 256 blocks x 256 thr (1 block/CU). Block cg owns 8 h-channels
// c in [cg*8, cg*8+8): 24 W-rows (r,z,n) live in LDS (144 KB, loaded once).
// Two MFMA B-tiles per block: T0 = [r0-7 | z0-7] (fused x+h K),
// T1 = [n0-7 | r-dup] with separate x/h accumulators (n-gate needs i_n, h_n split).
// Wave w = K-quarter over all 64 batch rows: per k-iter 4 A-loads + 2 ds_reads
// -> 8 MFMAs. K-reduce via 12 KB LDS scratch (3 rounds) into wave 0, which
// evaluates gates entirely from registers. One 2-level device barrier per step.
//
// ws: Wc fp16 [6144][3072] | XA fp16 [257][64][1024] | Hbuf fp16 [2][64][2048]
//     rpart f32 [2][64][256] | bar u32[1024]

#define HT    2048
#define INW   1024
#define KTOT  3072
#define G3    6144
#define BB    64
#define TRR   256
#define NSTEP 257
#define NBLK  256
#define NTHR  256

#define LDS_STRIDE 6160                    // 6144 + 16 pad (banks: row*1540 %32 = 4*row)
#define LDS_W_BYTES (24 * LDS_STRIDE)      // 147840
#define LDS_SCRATCH 12288                  // 12 v4f x 64 lanes x 4 B
#define LDS_TOTAL (LDS_W_BYTES + LDS_SCRATCH)  // 160128 <= 163840

typedef _Float16 f16;
typedef _Float16 half8 __attribute__((ext_vector_type(8)));
typedef _Float16 half4x __attribute__((ext_vector_type(4)));
typedef float v4f __attribute__((ext_vector_type(4)));

__device__ __forceinline__ float sigm_(float x) {
  x = fminf(fmaxf(x, -30.f), 30.f);
  return 1.f / (1.f + __expf(-x));
}
__device__ __forceinline__ float tanh_(float x) {
  x = fminf(fmaxf(x, -15.f), 15.f);
  float e = __expf(2.f * x);
  return (e - 1.f) / (e + 1.f);
}

__global__ void prep_weights(const float* __restrict__ Wih, const float* __restrict__ Whh,
                             f16* __restrict__ Wc) {
  long idx = (long)blockIdx.x * blockDim.x + threadIdx.x;
  const long total = (long)G3 * KTOT / 4;
  if (idx >= total) return;
  long e = idx * 4;
  int j = (int)(e / KTOT);
  int k = (int)(e % KTOT);
  float4 v;
  if (k < INW) v = *(const float4*)(Wih + (long)j * INW + k);
  else         v = *(const float4*)(Whh + (long)j * HT + (k - INW));
  half4x h = { (f16)v.x, (f16)v.y, (f16)v.z, (f16)v.w };
  *(half4x*)(Wc + e) = h;
}

__global__ void prep_inputs(const float* __restrict__ ha, const float* __restrict__ a,
                            const float* __restrict__ hs,
                            f16* __restrict__ XA, f16* __restrict__ H0,
                            unsigned* __restrict__ bar) {
  long idx = (long)blockIdx.x * blockDim.x + threadIdx.x;
  const long nxa = (long)NSTEP * BB * INW / 4;   // 4,210,688
  const long nh  = (long)BB * HT / 4;            // 32,768
  if (idx < nxa) {
    long e = idx * 4;
    int t = (int)(e >> 16);
    int rem = (int)(e & 65535);
    int b = rem >> 10;
    int k = rem & 1023;
    const float* src = (t == 0) ? (ha + ((long)b * TRR + 255) * INW + k)
                                : (a  + ((long)b * TRR + (t - 1)) * INW + k);
    float4 v = *(const float4*)src;
    half4x h = { (f16)v.x, (f16)v.y, (f16)v.z, (f16)v.w };
    *(half4x*)(XA + e) = h;
  } else if (idx < nxa + nh) {
    long e = (idx - nxa) * 4;
    int b = (int)(e >> 11);
    int i = (int)(e & 2047);
    float4 v = *(const float4*)(hs + ((long)b * TRR + 255) * HT + i);
    half4x h = { (f16)v.x, (f16)v.y, (f16)v.z, (f16)v.w };
    *(half4x*)(H0 + e) = h;
  } else if (idx < nxa + nh + 1024) {
    bar[idx - (nxa + nh)] = 0u;                  // counters + root + gen
  }
}

// bar layout (uint indices): cnt[g] at g*32 (g=0..7), root at 256, gen at 288.
#define BAR_ROOT 256
#define BAR_GEN  288

__global__ void __launch_bounds__(NTHR)
gru_persist(const f16* __restrict__ Wc, const f16* __restrict__ XA,
            f16* __restrict__ Hbuf, float* __restrict__ rpart,
            unsigned* __restrict__ bar,
            const float* __restrict__ bih, const float* __restrict__ bhh,
            const float* __restrict__ Wr, const float* __restrict__ brp,
            float* __restrict__ out) {
  extern __shared__ char smem[];
  const int bid = blockIdx.x;          // channel group: c in [bid*8, bid*8+8)
  const int c0  = bid * 8;
  const int tid = threadIdx.x;
  const int w   = tid >> 6;            // wave id = K-quarter
  const int l   = tid & 63;
  const int q   = l >> 4;              // quad -> k sub-offset q*8
  const int ci  = l & 15;              // B-tile column

  // ---- stage 24 weight rows into LDS (once) ----
  // LDS row u: u<8 -> r rows, 8..15 -> z, 16..23 -> n ; global row j = g*HT + c0 + ch
  for (int cch = tid; cch < 24 * 384; cch += NTHR) {   // 16B chunks
    int u = cch / 384, off = (cch % 384) * 16;
    int g = u >> 3, ch = u & 7;
    long j = (long)g * HT + c0 + ch;
    *(float4*)(smem + (long)u * LDS_STRIDE + off) =
        *(const float4*)((const char*)Wc + j * (KTOT * 2) + off);
  }
  __syncthreads();

  // per-lane B-frag LDS bases
  const char* bT0 = smem + (long)ci * LDS_STRIDE + q * 16;                       // [r|z]
  const char* bT1 = smem + (long)(ci < 8 ? 16 + ci : ci - 8) * LDS_STRIDE + q * 16; // [n|dup]
  float* scr = (float*)(smem + LDS_W_BYTES);

  // gate constants for wave 0 lanes ci<8 (channel c = c0 + ci)
  const int c = c0 + (ci & 7);
  const float bi_r = bih[c],          bh_r = bhh[c];
  const float bi_z = bih[HT + c],     bh_z = bhh[HT + c];
  const float bi_n = bih[2 * HT + c], bh_n = bhh[2 * HT + c];
  const float wr = Wr[c];
  const float br = brp[0];
  float* outr = out;                        // [64][256]
  float* outs = out + (long)BB * TRR;       // [64][256][2048]

  for (int t = 0; t <= 256; ++t) {
    const f16* Xt  = XA + (long)t * BB * INW;
    const f16* Hin = Hbuf + (long)(t & 1) * BB * HT;
    f16* Hout      = Hbuf + (long)((t + 1) & 1) * BB * HT;

    v4f acc[12];                            // [0..3]=T0(rt), [4..7]=T1x, [8..11]=T1h
    #pragma unroll
    for (int i = 0; i < 12; ++i) acc[i] = (v4f){0.f, 0.f, 0.f, 0.f};

    // ---- x-side K-iters (pre-barrier: XA immutable, weights in LDS) ----
    #pragma unroll 4
    for (int j = 0; j < 8; ++j) {
      int k = w * 256 + j * 32;             // 0..1023
      half8 b0 = *(const half8*)(bT0 + (long)k * 2);
      half8 b1 = *(const half8*)(bT1 + (long)k * 2);
      #pragma unroll
      for (int rt = 0; rt < 4; ++rt) {
        half8 a = *(const half8*)(Xt + (long)(rt * 16 + ci) * INW + k + q * 8);
        acc[rt]     = __builtin_amdgcn_mfma_f32_16x16x32_f16(a, b0, acc[rt], 0, 0, 0);
        acc[4 + rt] = __builtin_amdgcn_mfma_f32_16x16x32_f16(a, b1, acc[4 + rt], 0, 0, 0);
      }
    }

    // ---- wait for h_{t-1} ----
    if (t > 0) {
      if (tid == 0) {
        while (__hip_atomic_load(&bar[BAR_GEN], __ATOMIC_ACQUIRE,
                                 __HIP_MEMORY_SCOPE_AGENT) < (unsigned)t)
          __builtin_amdgcn_s_sleep(2);
      }
      __syncthreads();   // S1
    }

    // ---- h-side K-iters ----
    #pragma unroll 4
    for (int j = 0; j < 16; ++j) {
      int kl = w * 512 + j * 32;            // 0..2047
      half8 b0 = *(const half8*)(bT0 + (long)(INW + kl) * 2);
      half8 b1 = *(const half8*)(bT1 + (long)(INW + kl) * 2);
      #pragma unroll
      for (int rt = 0; rt < 4; ++rt) {
        half8 a = *(const half8*)(Hin + (long)(rt * 16 + ci) * HT + kl + q * 8);
        acc[rt]     = __builtin_amdgcn_mfma_f32_16x16x32_f16(a, b0, acc[rt], 0, 0, 0);
        acc[8 + rt] = __builtin_amdgcn_mfma_f32_16x16x32_f16(a, b1, acc[8 + rt], 0, 0, 0);
      }
    }
    __syncthreads();     // S2

    // ---- K-reduce waves 1..3 into wave 0 (12 KB scratch, 3 rounds) ----
    for (int s = 1; s <= 3; ++s) {
      if (w == s) {
        #pragma unroll
        for (int v = 0; v < 12; ++v) *(v4f*)(scr + (v * 64 + l) * 4) = acc[v];
      }
      __syncthreads();
      if (w == 0) {
        #pragma unroll
        for (int v = 0; v < 12; ++v) acc[v] += *(const v4f*)(scr + (v * 64 + l) * 4);
      } else if (s == 1 && w == 1 && bid < BB && t >= 2) {
        // finalize reward for step t-2 (row = bid), off critical path
        const float* rp = rpart + (long)((t - 1) & 1) * BB * NBLK + (long)bid * NBLK;
        float v = rp[l] + rp[l + 64] + rp[l + 128] + rp[l + 192];
        v += __shfl_xor(v, 32, 64); v += __shfl_xor(v, 16, 64);
        v += __shfl_xor(v, 8, 64);  v += __shfl_xor(v, 4, 64);
        v += __shfl_xor(v, 2, 64);  v += __shfl_xor(v, 1, 64);
        if (l == 0) outr[(long)bid * TRR + (t - 2)] = sigm_(v + br);
      }
      __syncthreads();
    }

    // ---- gates (wave 0): C/D row = rt*16 + q*4 + rr, T0 col ci: r(ci<8)|z(ci-8) ----
    if (w == 0) {
      #pragma unroll
      for (int rt = 0; rt < 4; ++rt) {
        float zl[4];
        #pragma unroll
        for (int rr = 0; rr < 4; ++rr) zl[rr] = __shfl_xor(acc[rt][rr], 8, 16);
        if (ci < 8) {
          #pragma unroll
          for (int rr = 0; rr < 4; ++rr) {
            const int row = rt * 16 + q * 4 + rr;
            float rg = sigm_(acc[rt][rr] + bi_r + bh_r);
            float zg = sigm_(zl[rr] + bi_z + bh_z);
            float ng = tanh_(acc[4 + rt][rr] + bi_n + rg * (acc[8 + rt][rr] + bh_n));
            float hp = (float)Hin[(long)row * HT + c];
            float hn = (1.f - zg) * ng + zg * hp;
            Hout[(long)row * HT + c] = (f16)hn;
            if (t >= 1)
              __builtin_nontemporal_store(hn, outs + ((long)row * TRR + (t - 1)) * HT + c);
            float v = hn * wr;
            v += __shfl_xor(v, 1, 8); v += __shfl_xor(v, 2, 8); v += __shfl_xor(v, 4, 8);
            if (ci == 0)
              rpart[(long)(t & 1) * BB * NBLK + (long)row * NBLK + bid] = v;
          }
        }
      }
    }

    // ---- arrive (2-level: 8 per-XCD counters + root; monotone, masked) ----
    __syncthreads();     // drains all waves' stores before release
    if (tid == 0) {
      int g = bid & 7;
      unsigned p = __hip_atomic_fetch_add(&bar[g * 32], 1u, __ATOMIC_ACQ_REL,
                                          __HIP_MEMORY_SCOPE_AGENT);
      if ((p & 31) == 31) {
        unsigned pr = __hip_atomic_fetch_add(&bar[BAR_ROOT], 1u, __ATOMIC_ACQ_REL,
                                             __HIP_MEMORY_SCOPE_AGENT);
        if ((pr & 7) == 7)
          __hip_atomic_store(&bar[BAR_GEN], (unsigned)(t + 1), __ATOMIC_RELEASE,
                             __HIP_MEMORY_SCOPE_AGENT);
      }
    }
  }

  // ---- final reward column (t=256 -> r_list[:,255], parity 0) ----
  if (tid == 0) {
    while (__hip_atomic_load(&bar[BAR_GEN], __ATOMIC_ACQUIRE,
                             __HIP_MEMORY_SCOPE_AGENT) < 257u)
      __builtin_amdgcn_s_sleep(2);
  }
  __syncthreads();
  if (w == 1 && bid < BB) {
    const float* rp = rpart + (long)bid * NBLK;   // parity (256)&1 = 0
    float v = rp[l] + rp[l + 64] + rp[l + 128] + rp[l + 192];
    v += __shfl_xor(v, 32, 64); v += __shfl_xor(v, 16, 64);
    v += __shfl_xor(v, 8, 64);  v += __shfl_xor(v, 4, 64);
    v += __shfl_xor(v, 2, 64);  v += __shfl_xor(v, 1, 64);
    if (l == 0) outr[(long)bid * TRR + 255] = sigm_(v + br);
  }
}

extern "C" void kernel_launch(void* const* d_in, const int* in_sizes, int n_in,
                              void* d_out, int out_size, void* d_ws, size_t ws_size,
                              hipStream_t stream) {
  const float* hs  = (const float*)d_in[0];
  const float* ha  = (const float*)d_in[1];
  /* d_in[2] = s — unused by the reference */
  const float* a   = (const float*)d_in[3];
  const float* Wih = (const float*)d_in[4];
  const float* Whh = (const float*)d_in[5];
  const float* bih = (const float*)d_in[6];
  const float* bhh = (const float*)d_in[7];
  const float* Wr  = (const float*)d_in[8];
  const float* br  = (const float*)d_in[9];
  float* out = (float*)d_out;

  char* ws = (char*)d_ws;
  const size_t oWc  = 0;
  const size_t oXA  = oWc + (size_t)G3 * KTOT * 2;           // 37,748,736
  const size_t oHb  = oXA + (size_t)NSTEP * BB * INW * 2;    // +33,685,504
  const size_t oRp  = oHb + (size_t)2 * BB * HT * 2;         // +524,288
  const size_t oBar = oRp + (size_t)2 * BB * NBLK * 4;       // +131,072
  f16* Wc   = (f16*)(ws + oWc);
  f16* XA   = (f16*)(ws + oXA);
  f16* Hb   = (f16*)(ws + oHb);
  float* rp = (float*)(ws + oRp);
  unsigned* bar = (unsigned*)(ws + oBar);

  (void)hipFuncSetAttribute(reinterpret_cast<const void*>(gru_persist),
                            hipFuncAttributeMaxDynamicSharedMemorySize, LDS_TOTAL);

  {
    long quads = (long)G3 * KTOT / 4;
    prep_weights<<<dim3((unsigned)((quads + 255) / 256)), dim3(256), 0, stream>>>(Wih, Whh, Wc);
  }
  {
    long ntot = (long)NSTEP * BB * INW / 4 + (long)BB * HT / 4 + 1024;
    prep_inputs<<<dim3((unsigned)((ntot + 255) / 256)), dim3(256), 0, stream>>>(ha, a, hs, XA, Hb, bar);
  }
  {
    void* args[] = { &Wc, &XA, &Hb, &rp, &bar,
                     (void*)&bih, (void*)&bhh, (void*)&Wr, (void*)&br, &out };
    hipLaunchCooperativeKernel(reinterpret_cast<void*>(gru_persist),
                               dim3(NBLK), dim3(NTHR), args, LDS_TOTAL, stream);
  }
}